// Round 2
// baseline (124.969 us; speedup 1.0000x reference)
//
#include <hip/hip_runtime.h>
#include <stdint.h>

// Problem shape (fixed by setup_inputs): B=16, C=64, H=128, W=128, fp32 throughout
#define CCH   64
#define HWSZ  16384          // H*W = 2^14
#define BATCH 16
#define NPC   (BATCH * HWSZ) // elements per channel = 262144
#define NTOT  (BATCH * CCH * HWSZ)  // 16,777,216 floats

static constexpr float COS_RY = 0.99500416527802576610f; // cos(0.1)
static constexpr float EPS    = 1e-6f;

__device__ __forceinline__ float qpix(float x) {
    // z = cos(0.1)*cos(x); q = z + z^2 + z^3 + z^4
    float z = COS_RY * __cosf(x);
    return z * (1.0f + z * (1.0f + z * (1.0f + z)));
}

// Pass 1: per-channel sum(q), sum(q^2).
// grid = BATCH*CCH = 1024 blocks; block b*C+c owns the contiguous 16384-float slab.
__global__ __launch_bounds__(256) void stats_kernel(
        const float* __restrict__ x, float* __restrict__ ws) {
    const int blk = blockIdx.x;          // b*CCH + c
    const int c   = blk & (CCH - 1);
    const float4* p = (const float4*)(x + (size_t)blk * HWSZ);

    float s = 0.0f, s2 = 0.0f;
    // 16384 floats / (256 thr * 4/vec) = 16 iterations
    #pragma unroll
    for (int it = 0; it < 16; ++it) {
        const float4 v = p[it * 256 + (int)threadIdx.x];
        const float q0 = qpix(v.x);
        const float q1 = qpix(v.y);
        const float q2 = qpix(v.z);
        const float q3 = qpix(v.w);
        s  += (q0 + q1) + (q2 + q3);
        s2 += (q0 * q0 + q1 * q1) + (q2 * q2 + q3 * q3);
    }
    // wave-64 shuffle reduce
    #pragma unroll
    for (int off = 32; off > 0; off >>= 1) {
        s  += __shfl_down(s,  off, 64);
        s2 += __shfl_down(s2, off, 64);
    }
    __shared__ float ls[4], ls2[4];
    const int wave = threadIdx.x >> 6;
    const int lane = threadIdx.x & 63;
    if (lane == 0) { ls[wave] = s; ls2[wave] = s2; }
    __syncthreads();
    if (threadIdx.x == 0) {
        const float ts  = (ls[0]  + ls[1])  + (ls[2]  + ls[3]);
        const float ts2 = (ls2[0] + ls2[1]) + (ls2[2] + ls2[3]);
        atomicAdd(&ws[c],       ts);    // device-scope by default
        atomicAdd(&ws[CCH + c], ts2);
    }
}

// Pass 2: y = relu((q - mean)*rsqrt(var+eps)*gamma + beta) + x
__global__ __launch_bounds__(256) void apply_kernel(
        const float* __restrict__ x,
        const float* __restrict__ gamma,
        const float* __restrict__ beta,
        const float* __restrict__ ws,
        float* __restrict__ out) {
    const size_t vi   = (size_t)blockIdx.x * 256 + threadIdx.x; // float4 index
    const size_t base = vi * 4;
    const int c = (int)((base >> 14) & (CCH - 1)); // HWSZ=2^14; vec4 never straddles a slab

    const float invn  = 1.0f / (float)NPC;
    const float mean  = ws[c] * invn;
    const float var   = ws[CCH + c] * invn - mean * mean;
    const float inv   = rsqrtf(var + EPS);
    const float scale = gamma[c] * inv;
    const float shift = beta[c] - mean * scale;

    const float4 v = *(const float4*)(x + base);
    float4 o;
    o.x = fmaxf(qpix(v.x) * scale + shift, 0.0f) + v.x;
    o.y = fmaxf(qpix(v.y) * scale + shift, 0.0f) + v.y;
    o.z = fmaxf(qpix(v.z) * scale + shift, 0.0f) + v.z;
    o.w = fmaxf(qpix(v.w) * scale + shift, 0.0f) + v.w;
    *(float4*)(out + base) = o;
}

extern "C" void kernel_launch(void* const* d_in, const int* in_sizes, int n_in,
                              void* d_out, int out_size, void* d_ws, size_t ws_size,
                              hipStream_t stream) {
    const float* x     = (const float*)d_in[0];
    const float* gamma = (const float*)d_in[1];
    const float* beta  = (const float*)d_in[2];
    float* out = (float*)d_out;
    float* ws  = (float*)d_ws;

    // d_ws is re-poisoned to 0xAA before every timed launch — zero our 128 floats.
    hipMemsetAsync(ws, 0, 2 * CCH * sizeof(float), stream);

    stats_kernel<<<BATCH * CCH, 256, 0, stream>>>(x, ws);

    const int nvec   = NTOT / 4;   // 4,194,304 float4 units
    const int blocks = nvec / 256; // 16384 blocks
    apply_kernel<<<blocks, 256, 0, stream>>>(x, gamma, beta, ws, out);
}